// Round 2
// baseline (720.769 us; speedup 1.0000x reference)
//
#include <hip/hip_runtime.h>
#include <hip/hip_bf16.h>

// ---------------- problem constants ----------------
#define T_TOK 2048
#define DMODEL 1024
#define DMLP 4096
#define NEXP 8
#define YB 4  // live m-tile blocks per expert (cnt ~512 = 4 x 128)

typedef __bf16 bf16x8 __attribute__((ext_vector_type(8)));
typedef float f32x4 __attribute__((ext_vector_type(4)));
typedef unsigned short u16x8 __attribute__((ext_vector_type(8)));

__device__ __forceinline__ unsigned short f2bf(float f) {
  return __builtin_bit_cast(unsigned short, (__bf16)f);
}

// ---------------- kernel 1: router ----------------
__global__ __launch_bounds__(64) void router_k(
    const float* __restrict__ x, const float* __restrict__ wg,
    int* __restrict__ topi, float* __restrict__ topw) {
  int t = blockIdx.x;
  int lane = threadIdx.x;
  const float* hx = x + (size_t)t * DMODEL;
  float acc[NEXP];
#pragma unroll
  for (int e = 0; e < NEXP; ++e) acc[e] = 0.f;
  for (int i = lane; i < DMODEL; i += 64) {
    float xi = hx[i];
    const float* w = wg + (size_t)i * NEXP;
#pragma unroll
    for (int e = 0; e < NEXP; ++e) acc[e] += xi * w[e];
  }
#pragma unroll
  for (int off = 32; off > 0; off >>= 1) {
#pragma unroll
    for (int e = 0; e < NEXP; ++e) acc[e] += __shfl_down(acc[e], off);
  }
  if (lane == 0) {
    float m = acc[0];
#pragma unroll
    for (int e = 1; e < NEXP; ++e) m = fmaxf(m, acc[e]);
    float p[NEXP], s = 0.f;
#pragma unroll
    for (int e = 0; e < NEXP; ++e) { p[e] = expf(acc[e] - m); s += p[e]; }
    float inv = 1.f / s;
#pragma unroll
    for (int e = 0; e < NEXP; ++e) p[e] *= inv;
    int i1 = 0;
#pragma unroll
    for (int e = 1; e < NEXP; ++e) if (p[e] > p[i1]) i1 = e;
    int i2 = (i1 == 0) ? 1 : 0;
#pragma unroll
    for (int e = 0; e < NEXP; ++e) if (e != i1 && p[e] > p[i2]) i2 = e;
    float w1 = p[i1], w2 = p[i2];
    float rs = 1.f / (w1 + w2);
    topi[2 * t] = i1;
    topi[2 * t + 1] = i2;
    topw[2 * t] = w1 * rs;
    topw[2 * t + 1] = w2 * rs;
  }
}

// ---------------- kernel 2: per-expert compaction (chunked, 8 waves) ------
__global__ __launch_bounds__(512) void compact_k(
    const int* __restrict__ topi, const float* __restrict__ topw,
    int* __restrict__ offsets, int* __restrict__ perm,
    float* __restrict__ wrow) {
  int tid = threadIdx.x;
  int w = tid >> 6, lane = tid & 63;
  __shared__ int hist[NEXP][NEXP];    // [wave][expert]
  __shared__ int base_s[NEXP][NEXP];  // [wave][expert]
  unsigned long long ltmask = (lane == 63) ? ~0ULL >> 1 : ((1ULL << lane) - 1ULL);

  int c[NEXP];
#pragma unroll
  for (int ex = 0; ex < NEXP; ++ex) c[ex] = 0;
  // phase 1: per-wave histogram of its 512-entry chunk
  for (int it = 0; it < 8; ++it) {
    int j = w * 512 + it * 64 + lane;
    int e = topi[j];
#pragma unroll
    for (int ex = 0; ex < NEXP; ++ex) {
      unsigned long long m = __ballot(e == ex);
      c[ex] += __popcll(m);
    }
  }
  if (lane == 0) {
#pragma unroll
    for (int ex = 0; ex < NEXP; ++ex) hist[w][ex] = c[ex];
  }
  __syncthreads();
  if (tid == 0) {
    int s = 0;
    for (int ex = 0; ex < NEXP; ++ex) {
      offsets[ex] = s;
      int t = s;
      for (int w2 = 0; w2 < NEXP; ++w2) { base_s[w2][ex] = t; t += hist[w2][ex]; }
      s = t;
    }
    offsets[NEXP] = s;
  }
  __syncthreads();
  int rb[NEXP];
#pragma unroll
  for (int ex = 0; ex < NEXP; ++ex) rb[ex] = base_s[w][ex];
  // phase 2: scatter
  for (int it = 0; it < 8; ++it) {
    int j = w * 512 + it * 64 + lane;
    int e = topi[j];
    float pw = topw[j];
#pragma unroll
    for (int ex = 0; ex < NEXP; ++ex) {
      unsigned long long m = __ballot(e == ex);
      if (e == ex) {
        int p = rb[ex] + __popcll(m & ltmask);
        perm[p] = j >> 1;
        wrow[p] = pw;
      }
      rb[ex] += __popcll(m);
    }
  }
}

// ---------------- kernel 3: fused gate/in GEMM + silu ----------------
// B staging: thread owns one column n (8 k-values), 8 coalesced scalar loads,
// one ds_write_b128 -> bank-balanced (pitch 40: 8 dwords/bank = minimum).
#define BPITCH 40

__global__ __launch_bounds__(256) void hid_k(
    const float* __restrict__ x, const float* __restrict__ weg,
    const float* __restrict__ wei, const int* __restrict__ offsets,
    const int* __restrict__ perm, const float* __restrict__ wrow,
    unsigned short* __restrict__ hid) {
  int e = blockIdx.z;
  int off = offsets[e], cnt = offsets[e + 1] - off;
  int nb = blockIdx.x * 64;
  const float* wg = weg + (size_t)e * DMODEL * DMLP;
  const float* wi = wei + (size_t)e * DMODEL * DMLP;

  __shared__ unsigned short As[128 * BPITCH];
  __shared__ unsigned short Bg[64 * BPITCH];
  __shared__ unsigned short Bi[64 * BPITCH];

  int tid = threadIdx.x;
  int lane = tid & 63, wid = tid >> 6;
  int wm = (wid & 1) * 64, wn = (wid >> 1) * 32;
  int lr = lane & 15, q = lane >> 4;

  // B task: column bn, k-octet kq
  int bn = tid & 63, kq = tid >> 6;
  const float* gsrc = wg + (size_t)(kq * 8) * DMLP + nb + bn;
  const float* isrc = wi + (size_t)(kq * 8) * DMLP + nb + bn;
  int bdst = bn * BPITCH + kq * 8;

  for (int m0 = blockIdx.y * 128; m0 < cnt; m0 += YB * 128) {
    // A staging plan: 1024 float4-tasks (128 rows x 8 k-groups), 4/thread
    const float* aptr[4];
    int adst[4];
#pragma unroll
    for (int it = 0; it < 4; ++it) {
      int task = tid + it * 256;
      int r = task >> 3, kc = (task & 7) * 4;
      int pl = m0 + r;
      int src = perm[off + ((pl < cnt) ? pl : 0)];
      aptr[it] = x + (size_t)src * DMODEL + kc;
      adst[it] = r * BPITCH + kc;
    }

    f32x4 accg[4][2], acci[4][2];
    f32x4 z = {0.f, 0.f, 0.f, 0.f};
#pragma unroll
    for (int i = 0; i < 4; ++i)
#pragma unroll
      for (int j = 0; j < 2; ++j) { accg[i][j] = z; acci[i][j] = z; }

    for (int k0 = 0; k0 < DMODEL; k0 += 32) {
      // ---- stage A (gathered fp32 -> bf16) ----
#pragma unroll
      for (int it = 0; it < 4; ++it) {
        float4 v = *(const float4*)(aptr[it] + k0);
        ushort4 u;
        u.x = f2bf(v.x); u.y = f2bf(v.y); u.z = f2bf(v.z); u.w = f2bf(v.w);
        *(ushort4*)(&As[adst[it]]) = u;
      }
      // ---- stage B: gather 8 k for one column, write b128 ----
      {
        const float* pg = gsrc + (size_t)k0 * DMLP;
        const float* pi = isrc + (size_t)k0 * DMLP;
        float gv[8], iv[8];
#pragma unroll
        for (int kr = 0; kr < 8; ++kr) {
          gv[kr] = pg[(size_t)kr * DMLP];
          iv[kr] = pi[(size_t)kr * DMLP];
        }
        u16x8 ug, ui;
#pragma unroll
        for (int kr = 0; kr < 8; ++kr) {
          ug[kr] = f2bf(gv[kr]);
          ui[kr] = f2bf(iv[kr]);
        }
        *(u16x8*)(&Bg[bdst]) = ug;
        *(u16x8*)(&Bi[bdst]) = ui;
      }
      __syncthreads();
      // ---- compute ----
      bf16x8 af[4], bgf[2], bif[2];
#pragma unroll
      for (int i = 0; i < 4; ++i)
        af[i] = *(const bf16x8*)(&As[(wm + i * 16 + lr) * BPITCH + q * 8]);
#pragma unroll
      for (int j = 0; j < 2; ++j) {
        bgf[j] = *(const bf16x8*)(&Bg[(wn + j * 16 + lr) * BPITCH + q * 8]);
        bif[j] = *(const bf16x8*)(&Bi[(wn + j * 16 + lr) * BPITCH + q * 8]);
      }
#pragma unroll
      for (int i = 0; i < 4; ++i)
#pragma unroll
        for (int j = 0; j < 2; ++j) {
          accg[i][j] = __builtin_amdgcn_mfma_f32_16x16x32_bf16(af[i], bgf[j], accg[i][j], 0, 0, 0);
          acci[i][j] = __builtin_amdgcn_mfma_f32_16x16x32_bf16(af[i], bif[j], acci[i][j], 0, 0, 0);
        }
      __syncthreads();
    }
    // ---- epilogue: silu(g)*v * wrow -> bf16 hid ----
#pragma unroll
    for (int i = 0; i < 4; ++i)
#pragma unroll
      for (int j = 0; j < 2; ++j)
#pragma unroll
        for (int r = 0; r < 4; ++r) {
          int row = wm + i * 16 + q * 4 + r;
          int pl = m0 + row;
          if (pl < cnt) {
            int pos = off + pl;
            float g = accg[i][j][r], vv = acci[i][j][r];
            float hv = (g / (1.f + expf(-g))) * vv * wrow[pos];
            hid[(size_t)pos * DMLP + nb + wn + j * 16 + lr] = f2bf(hv);
          }
        }
  }
}

// ---------------- kernel 4: out GEMM, atomic accumulate, K-split x2 -------
__global__ __launch_bounds__(256) void out_k(
    const unsigned short* __restrict__ hid, const float* __restrict__ weo,
    const int* __restrict__ offsets, const int* __restrict__ perm,
    float* __restrict__ out) {
  int e = blockIdx.z;
  int off = offsets[e], cnt = offsets[e + 1] - off;
  int kh = blockIdx.y & 1;      // K half: [kh*2048, kh*2048+2048)
  int yb = blockIdx.y >> 1;     // m-tile slot 0..3
  int nb = blockIdx.x * 64;
  const float* wo = weo + (size_t)e * DMLP * DMODEL;

  __shared__ unsigned short As[128 * BPITCH];
  __shared__ unsigned short Bs[64 * BPITCH];

  int tid = threadIdx.x;
  int lane = tid & 63, wid = tid >> 6;
  int wm = (wid & 1) * 64, wn = (wid >> 1) * 32;
  int lr = lane & 15, q = lane >> 4;

  // B task: column bn (of DMODEL), k-octet kq
  int bn = tid & 63, kq = tid >> 6;
  const float* bsrc = wo + (size_t)(kh * 2048 + kq * 8) * DMODEL + nb + bn;
  int bdst = bn * BPITCH + kq * 8;

  for (int m0 = yb * 128; m0 < cnt; m0 += YB * 128) {
    const unsigned short* aptr[2];
    int adst[2];
#pragma unroll
    for (int it = 0; it < 2; ++it) {
      int task = tid + it * 256;
      int r = task >> 2, kg = (task & 3) * 8;
      int pl = m0 + r;
      int src = off + ((pl < cnt) ? pl : 0);
      aptr[it] = hid + (size_t)src * DMLP + kh * 2048 + kg;
      adst[it] = r * BPITCH + kg;
    }

    f32x4 acc[4][2];
    f32x4 z = {0.f, 0.f, 0.f, 0.f};
#pragma unroll
    for (int i = 0; i < 4; ++i)
#pragma unroll
      for (int j = 0; j < 2; ++j) acc[i][j] = z;

    for (int kk = 0; kk < 2048; kk += 32) {
      // ---- stage A (bf16 passthrough, 16B) ----
#pragma unroll
      for (int it = 0; it < 2; ++it) {
        uint4 v = *(const uint4*)(aptr[it] + kk);
        *(uint4*)(&As[adst[it]]) = v;
      }
      // ---- stage B: gather 8 k for one column, write b128 ----
      {
        const float* pb = bsrc + (size_t)kk * DMODEL;
        float bv[8];
#pragma unroll
        for (int kr = 0; kr < 8; ++kr) bv[kr] = pb[(size_t)kr * DMODEL];
        u16x8 ub;
#pragma unroll
        for (int kr = 0; kr < 8; ++kr) ub[kr] = f2bf(bv[kr]);
        *(u16x8*)(&Bs[bdst]) = ub;
      }
      __syncthreads();
      // ---- compute ----
      bf16x8 af[4], bfr[2];
#pragma unroll
      for (int i = 0; i < 4; ++i)
        af[i] = *(const bf16x8*)(&As[(wm + i * 16 + lr) * BPITCH + q * 8]);
#pragma unroll
      for (int j = 0; j < 2; ++j)
        bfr[j] = *(const bf16x8*)(&Bs[(wn + j * 16 + lr) * BPITCH + q * 8]);
#pragma unroll
      for (int i = 0; i < 4; ++i)
#pragma unroll
        for (int j = 0; j < 2; ++j)
          acc[i][j] = __builtin_amdgcn_mfma_f32_16x16x32_bf16(af[i], bfr[j], acc[i][j], 0, 0, 0);
      __syncthreads();
    }
    // ---- epilogue: scatter-add into out ----
#pragma unroll
    for (int i = 0; i < 4; ++i)
#pragma unroll
      for (int j = 0; j < 2; ++j)
#pragma unroll
        for (int r = 0; r < 4; ++r) {
          int row = wm + i * 16 + q * 4 + r;
          int pl = m0 + row;
          if (pl < cnt) {
            int tok = perm[off + pl];
            atomicAdd(&out[(size_t)tok * DMODEL + nb + wn + j * 16 + lr],
                      acc[i][j][r]);
          }
        }
  }
}

// ---------------- launcher ----------------
extern "C" void kernel_launch(void* const* d_in, const int* in_sizes, int n_in,
                              void* d_out, int out_size, void* d_ws,
                              size_t ws_size, hipStream_t stream) {
  const float* x = (const float*)d_in[0];
  const float* wgate = (const float*)d_in[1];
  const float* weg = (const float*)d_in[2];
  const float* wei = (const float*)d_in[3];
  const float* weo = (const float*)d_in[4];
  float* out = (float*)d_out;

  char* ws = (char*)d_ws;
  int* topi = (int*)(ws + 0);
  float* topw = (float*)(ws + (16 << 10));
  int* offsets = (int*)(ws + (32 << 10));
  int* perm = (int*)(ws + (33 << 10));
  float* wrow = (float*)(ws + (49 << 10));
  unsigned short* hid = (unsigned short*)(ws + (65 << 10));  // 4096x4096 bf16

  hipMemsetAsync(d_out, 0, (size_t)out_size * sizeof(float), stream);
  router_k<<<dim3(T_TOK), dim3(64), 0, stream>>>(x, wgate, topi, topw);
  compact_k<<<dim3(1), dim3(512), 0, stream>>>(topi, topw, offsets, perm, wrow);
  hid_k<<<dim3(DMLP / 64, YB, NEXP), dim3(256), 0, stream>>>(
      x, weg, wei, offsets, perm, wrow, hid);
  out_k<<<dim3(DMODEL / 64, 2 * YB, NEXP), dim3(256), 0, stream>>>(
      hid, weo, offsets, perm, out);
}